// Round 8
// baseline (957.310 us; speedup 1.0000x reference)
//
#include <hip/hip_runtime.h>
#include <math.h>

#define NB 128
#define NS 256
#define NH 768
#define NL 24
#define SCLS 28   // scl row stride (words): 112B rows, 16B-aligned; col 24+ = pad

// ---------------- Kernel A: emissions = sigmoid(tf[b,t+1,:] @ W + b) for t < n_b ----
// v7: lane = token (64-token tiles, proven A-pattern from R6), 4 waves split K
// (192 k each, same summation order as R6 -> E bitwise-identical to a passing
// kernel). W flows global -> reg (prefetch issued before compute; ~2240 cyc of
// FMA covers the latency) -> LDS chunk [4][32][24] double-buffered -> read as
// wave-uniform 1-address ds_read_b128 broadcast (vs R4's 4-address: ~3x cheaper
// per instr, 4x fewer wave-instrs). launch_bounds(256,2) keeps prefetch in VGPRs.
__global__ __launch_bounds__(256, 2) void ner_emis(
    const float* __restrict__ tf, const int* __restrict__ tlm,
    const float* __restrict__ W, const float* __restrict__ bias,
    float* __restrict__ E)
{
    const int b    = blockIdx.x >> 2;
    const int tile = (blockIdx.x & 3) << 6;         // token base (64-token tile)
    const int tid  = threadIdx.x;
    if (tlm[b*NS + tile] == 0) return;              // prefix mask: whole tile invalid

    __shared__ __align__(16) float lds[6400];       // union: Ws 2*768 f4 (24 KB) / Pr 25.6 KB
    float4* Ws4 = (float4*)lds;                     // [2][4 kseg][32 row][6 f4]
    float*  Pr  = lds;                              // [4][64][25] partials (after K-loop)

    const int lane = tid & 63;                      // token within tile
    const int wu   = __builtin_amdgcn_readfirstlane(tid >> 6);  // kseg 0..3 (uniform)
    const int ks   = wu * 192;                      // this wave's k range

    int trow = tile + lane + 1;                     // feature row = token+1
    if (trow > 255) trow = 255;                     // clamp (row invalid anyway)
    const float* srcA = tf + ((size_t)b*NS + trow)*NH + ks;

    // W staging map: chunk = 4 kseg x 32 rows x 24 = 768 float4; 3 per thread.
    // i = tid + j*256: kg = i/192, f = i%192 (row = f/6, c4 = f%6)
    // global f4 idx = kg*1152 + ch*192 + f ; LDS f4 idx = buf*768 + i
    int ib[3], gb[3];
    #pragma unroll
    for (int j = 0; j < 3; ++j) {
        int i  = tid + (j << 8);
        int kg = i / 192, f = i % 192;
        ib[j] = i;
        gb[j] = kg*1152 + f;
    }
    const float4* W4 = (const float4*)W;

    float acc[NL];
    #pragma unroll
    for (int l = 0; l < NL; ++l) acc[l] = 0.f;

    auto fma24row = [&](float av, const float4* p) {
        float4 u0 = p[0], u1 = p[1], u2 = p[2], u3 = p[3], u4 = p[4], u5 = p[5];
        acc[0]  = fmaf(av, u0.x, acc[0]);  acc[1]  = fmaf(av, u0.y, acc[1]);
        acc[2]  = fmaf(av, u0.z, acc[2]);  acc[3]  = fmaf(av, u0.w, acc[3]);
        acc[4]  = fmaf(av, u1.x, acc[4]);  acc[5]  = fmaf(av, u1.y, acc[5]);
        acc[6]  = fmaf(av, u1.z, acc[6]);  acc[7]  = fmaf(av, u1.w, acc[7]);
        acc[8]  = fmaf(av, u2.x, acc[8]);  acc[9]  = fmaf(av, u2.y, acc[9]);
        acc[10] = fmaf(av, u2.z, acc[10]); acc[11] = fmaf(av, u2.w, acc[11]);
        acc[12] = fmaf(av, u3.x, acc[12]); acc[13] = fmaf(av, u3.y, acc[13]);
        acc[14] = fmaf(av, u3.z, acc[14]); acc[15] = fmaf(av, u3.w, acc[15]);
        acc[16] = fmaf(av, u4.x, acc[16]); acc[17] = fmaf(av, u4.y, acc[17]);
        acc[18] = fmaf(av, u4.z, acc[18]); acc[19] = fmaf(av, u4.w, acc[19]);
        acc[20] = fmaf(av, u5.x, acc[20]); acc[21] = fmaf(av, u5.y, acc[21]);
        acc[22] = fmaf(av, u5.z, acc[22]); acc[23] = fmaf(av, u5.w, acc[23]);
    };

    // ---- prologue: stage chunk 0 (W -> LDS buf0), load A chunk 0 ----
    {
        float4 t0 = W4[gb[0]], t1 = W4[gb[1]], t2 = W4[gb[2]];
        Ws4[ib[0]] = t0; Ws4[ib[1]] = t1; Ws4[ib[2]] = t2;
    }
    float4 aCur[8];
    #pragma unroll
    for (int q = 0; q < 8; ++q) aCur[q] = *(const float4*)(srcA + (q << 2));
    __syncthreads();

    int buf = 0;
    for (int ch = 0; ch < 6; ++ch) {                // 6 chunks of 32 k
        float4 wn0, wn1, wn2, aN[8];
        const bool more = (ch < 5);
        if (more) {                                  // issue next chunk's loads now
            const int g = (ch + 1) * 192;
            wn0 = W4[gb[0] + g]; wn1 = W4[gb[1] + g]; wn2 = W4[gb[2] + g];
            const float* sa = srcA + ((ch + 1) << 5);
            #pragma unroll
            for (int q = 0; q < 8; ++q) aN[q] = *(const float4*)(sa + (q << 2));
        }
        // compute chunk ch: 32 rows, W rows wave-uniform broadcast
        const float4* wrow = Ws4 + buf*768 + wu*192;
        #pragma unroll
        for (int q = 0; q < 8; ++q) {
            float4 aq = aCur[q];
            const float4* p = wrow + (q << 2)*6;
            fma24row(aq.x, p);
            fma24row(aq.y, p + 6);
            fma24row(aq.z, p + 12);
            fma24row(aq.w, p + 18);
        }
        __syncthreads();                            // all reads of buf done
        if (more) {
            Ws4[(buf ^ 1)*768 + ib[0]] = wn0;
            Ws4[(buf ^ 1)*768 + ib[1]] = wn1;
            Ws4[(buf ^ 1)*768 + ib[2]] = wn2;
            #pragma unroll
            for (int q = 0; q < 8; ++q) aCur[q] = aN[q];
            __syncthreads();                        // buf^1 ready
            buf ^= 1;
        }
    }

    // ---- fold 4 wave-partials in fixed order, sigmoid, masked store (as R6) ----
    {
        float* p = Pr + ((wu << 6) + lane)*25;
        #pragma unroll
        for (int l = 0; l < NL; ++l) p[l] = acc[l];
    }
    __syncthreads();

    const int* tm = tlm + b*NS + tile;
    float* Eb = E + (size_t)(b*NS + tile)*NL;
    #pragma unroll
    for (int i = 0; i < 6; ++i) {
        int o = tid + (i << 8);                     // 0..1535 (64 tok x 24 lab)
        int t = o / NL, l = o - t*NL;
        if (tm[t]) {
            float s = ((Pr[t*25 + l] + Pr[(64 + t)*25 + l])
                       + Pr[(128 + t)*25 + l]) + Pr[(192 + t)*25 + l];
            float x = s + bias[l];
            Eb[o] = 1.0f/(1.0f + expf(-x));
        }
    }
}

// ---------------- Kernel B: masked Viterbi decode, one block (256 thr) per batch ----
// Round-4 version verbatim (probe-measured 33.5 us, passed): 2-lanes-per-tag split,
// 12 ds_bpermute per step, permlane32_swap combine.
__global__ __launch_bounds__(256) void ner_viterbi(
    const float* __restrict__ E, const int* __restrict__ tlm,
    const float* __restrict__ trans, const float* __restrict__ st,
    const float* __restrict__ en, int* __restrict__ out)
{
    const int tid = threadIdx.x;
    const int b   = blockIdx.x;
    const int bS  = b*NS;

    __shared__ __align__(16) float Esh[NS*NL];   // preloaded emissions (24 KB)
    __shared__ __align__(16) float scl[NS*SCLS]; // per-step score vectors (28 KB)
    __shared__ __align__(16) float Tt[NL*NL];    // Tt[c*24+p] = T[p][c]
    __shared__ float fin[32];
    __shared__ unsigned char tr_s[NL][NS];  // trace[hypothesis][t]
    __shared__ int chosen[12];
    __shared__ int nsh, ltag;

    {
        const float4* src = (const float4*)(E + (size_t)bS*NL);
        float4* dst = (float4*)Esh;
        #pragma unroll
        for (int j = 0; j < 6; ++j) dst[tid + (j << 8)] = src[tid + (j << 8)];
    }
    for (int i = tid; i < NL*NL; i += 256) {
        int c = i / NL, p = i % NL;
        Tt[i] = trans[p*NL + c];
    }
    if (tid < 64) {   // n = lengths[b]-2 (contiguous prefix mask)
        int a = tlm[bS+tid] + tlm[bS+tid+64] + tlm[bS+tid+128] + tlm[bS+tid+192];
        #pragma unroll
        for (int off = 32; off > 0; off >>= 1) a += __shfl_down(a, off, 64);
        if (tid == 0) nsh = a;
    }
    __syncthreads();
    const int n = nsh;   // n >= 1 always

    // ---- forward: all 64 lanes of wave 0; lanes c and c+32 both own tag c ----
    if (tid < 64) {
        const int lane = tid;
        const int h    = lane >> 5;          // half: prev-tags [12h, 12h+12)
        const int c    = lane & 31;          // tag; c>=24 lanes garbage (never sourced)
        const int cidx = (c < 24) ? c : 23;  // clamped index for global reads
        const int coff = (c < 24) ? c : 24;  // scl column (24 = pad)
        const int p0   = h * 12;

        float Tc[12];
        #pragma unroll
        for (int j = 0; j < 12; ++j) Tc[j] = trans[(p0 + j)*NL + cidx];

        int idxv[12];
        #pragma unroll
        for (int j = 0; j < 12; ++j) idxv[j] = (p0 + j) << 2;

        auto bp = [](int idx4, float v) {   // pull lane (idx4/4)'s v — bit-exact
            return __int_as_float(__builtin_amdgcn_ds_bpermute(idx4, __float_as_int(v)));
        };

        float sv = st[cidx] + Esh[cidx];     // identical in lanes c and c+32
        scl[coff] = sv;                      // t=0 score vector (for backtrack)

        auto step = [&](int t, float em) {
            float cand[12];
            #pragma unroll
            for (int j = 0; j < 12; ++j)     // 12 indep bpermutes (halved DS-pipe)
                cand[j] = bp(idxv[j], sv) + Tc[j];
            float a0 = fmaxf(fmaxf(cand[0], cand[1]),  cand[2]);
            float a1 = fmaxf(fmaxf(cand[3], cand[4]),  cand[5]);
            float a2 = fmaxf(fmaxf(cand[6], cand[7]),  cand[8]);
            float a3 = fmaxf(fmaxf(cand[9], cand[10]), cand[11]);
            float pm = fmaxf(fmaxf(a0, a1), fmaxf(a2, a3));   // partial over 12 prevs
#if __has_builtin(__builtin_amdgcn_permlane32_swap)
            auto r = __builtin_amdgcn_permlane32_swap(
                         __float_as_int(pm), __float_as_int(pm), false, false);
            float best = fmaxf(__int_as_float(r[0]), __int_as_float(r[1]));
#else
            float best = fmaxf(pm, bp((lane ^ 32) << 2, pm));
#endif
            sv = best + em;
            scl[t*SCLS + coff] = sv;         // off critical path (backtrack input)
        };

        int t = 1;
        for (; t + 8 <= n; t += 8) {
            float em[8];
            const float* eb = Esh + t*NL + cidx;
            #pragma unroll
            for (int j = 0; j < 8; ++j) em[j] = eb[j*NL];   // 8 indep ds_read, imm offs
            #pragma unroll
            for (int j = 0; j < 8; ++j) step(t + j, em[j]);
        }
        for (; t < n; ++t) step(t, Esh[t*NL + cidx]);
        fin[c] = sv + en[cidx];              // c>=24 -> pad slots of fin[32]
    }
    __syncthreads();

    if (tid == 0) {   // argmax(final), first-max tie rule like jnp.argmax
        float bv = fin[0]; int bt = 0;
        #pragma unroll
        for (int cc = 1; cc < 24; ++cc) { if (fin[cc] > bv) { bv = fin[cc]; bt = cc; } }
        ltag = bt;
    }
    __syncthreads();

    // ---- backtrack: 10 windows x 24 hypotheses, recompute backpointers ----
    const int K = (n > 1) ? (n - 1 + 9) / 10 : 1;
    if (n > 1 && tid < 240) {
        const int w = tid / 24 + 1, h = tid % 24;
        int tlo = (w-1)*K; if (tlo > n-1) tlo = n-1;
        int thi = w*K;     if (thi > n-1) thi = n-1;
        int cur = h;
        for (int t = thi; t > tlo; --t) {
            const float4* sp = (const float4*)(scl + (t-1)*SCLS);
            const float4* up = (const float4*)(Tt  + cur*NL);
            float cand[24];
            #pragma unroll
            for (int i = 0; i < 6; ++i) {
                float4 s = sp[i], u = up[i];
                cand[4*i+0] = s.x + u.x;     // bitwise-identical to forward cand
                cand[4*i+1] = s.y + u.y;
                cand[4*i+2] = s.z + u.z;
                cand[4*i+3] = s.w + u.w;
            }
            float best = cand[0]; int arg = 0;
            #pragma unroll
            for (int p = 1; p < 24; ++p) { if (cand[p] > best) { best = cand[p]; arg = p; } }
            tr_s[h][t-1] = (unsigned char)arg;
            cur = arg;
        }
    }
    __syncthreads();

    if (tid == 0) {   // stitch windows
        int cur = ltag;
        for (int w = 10; w >= 1; --w) {
            chosen[w] = cur;
            int tlo = (w-1)*K; if (tlo > n-1) tlo = n-1;
            int thi = w*K;     if (thi > n-1) thi = n-1;
            if (thi > tlo) cur = tr_s[cur][tlo];
        }
    }
    __syncthreads();

    {   // emit path: t >= n-1 -> last_tag (identity backpointers on padding)
        const int t = tid;
        int tag;
        if (t >= n-1) tag = ltag;
        else { int w = t / K + 1; tag = tr_s[chosen[w]][t]; }
        out[bS + t] = tag;
    }
}

extern "C" void kernel_launch(void* const* d_in, const int* in_sizes, int n_in,
                              void* d_out, int out_size, void* d_ws, size_t ws_size,
                              hipStream_t stream) {
    const float* tf    = (const float*)d_in[0];
    const int*   tlm   = (const int*)  d_in[2];   // true_label_mask
    const float* W     = (const float*)d_in[3];
    const float* bias  = (const float*)d_in[4];
    const float* trans = (const float*)d_in[5];
    const float* st    = (const float*)d_in[6];
    const float* en    = (const float*)d_in[7];
    float* E = (float*)d_ws;                      // [128,256,24] fp32 = 3.1 MB

    ner_emis<<<dim3(NB*4), dim3(256), 0, stream>>>(tf, tlm, W, bias, E);
    ner_viterbi<<<dim3(NB), dim3(256), 0, stream>>>(E, tlm, trans, st, en, (int*)d_out);
}

// Round 9
// 220.309 us; speedup vs baseline: 4.3453x; 4.3453x over previous
//
#include <hip/hip_runtime.h>
#include <math.h>

#define NB 128
#define NS 256
#define NH 768
#define NL 24
#define SCLS 28   // scl row stride (words): 112B rows, 16B-aligned; col 24+ = pad

// ---------------- Kernel A: emissions = sigmoid(tf[b,t+1,:] @ W + b) for t < n_b ----
// v9 = R8's verified-correct v7 structure (passed, absmax 0) with the spill fixed:
//  - no launch_bounds VGPR cap (R8: cap 128 -> 1.24 GB scratch traffic, 803 us)
//  - A pipelined at 16-k granularity (4+4 float4 = 32 regs, was 64)
// lane = token (64-token tiles), 4 waves split K (192 k each, same summation order
// as the verified kernel). W: global -> reg -> LDS [2][4][32][24] double-buffered,
// read as wave-uniform 1-address ds_read_b128 broadcast (conflict-free).
__global__ __launch_bounds__(256) void ner_emis(
    const float* __restrict__ tf, const int* __restrict__ tlm,
    const float* __restrict__ W, const float* __restrict__ bias,
    float* __restrict__ E)
{
    const int b    = blockIdx.x >> 2;
    const int tile = (blockIdx.x & 3) << 6;         // token base (64-token tile)
    const int tid  = threadIdx.x;
    if (tlm[b*NS + tile] == 0) return;              // prefix mask: whole tile invalid

    __shared__ __align__(16) float lds[6400];       // union: Ws 2*768 f4 (24 KB) / Pr 25.6 KB
    float4* Ws4 = (float4*)lds;                     // [2][4 kseg][32 row][6 f4]
    float*  Pr  = lds;                              // [4][64][25] partials (after K-loop)

    const int lane = tid & 63;                      // token within tile
    const int wu   = __builtin_amdgcn_readfirstlane(tid >> 6);  // kseg 0..3 (uniform)
    const int ks   = wu * 192;                      // this wave's k range

    int trow = tile + lane + 1;                     // feature row = token+1
    if (trow > 255) trow = 255;                     // clamp (row invalid anyway)
    const float* srcA = tf + ((size_t)b*NS + trow)*NH + ks;

    // W staging map (verified in R8): chunk = 4 kseg x 32 rows x 24 = 768 float4;
    // 3 per thread. i = tid + j*256: kg = i/192, f = i%192.
    // global f4 idx = kg*1152 + ch*192 + f ; LDS f4 idx = buf*768 + i
    int ib[3], gb[3];
    #pragma unroll
    for (int j = 0; j < 3; ++j) {
        int i  = tid + (j << 8);
        int kg = i / 192, f = i % 192;
        ib[j] = i;
        gb[j] = kg*1152 + f;
    }
    const float4* W4 = (const float4*)W;

    float acc[NL];
    #pragma unroll
    for (int l = 0; l < NL; ++l) acc[l] = 0.f;

    auto fma24row = [&](float av, const float4* p) {
        float4 u0 = p[0], u1 = p[1], u2 = p[2], u3 = p[3], u4 = p[4], u5 = p[5];
        acc[0]  = fmaf(av, u0.x, acc[0]);  acc[1]  = fmaf(av, u0.y, acc[1]);
        acc[2]  = fmaf(av, u0.z, acc[2]);  acc[3]  = fmaf(av, u0.w, acc[3]);
        acc[4]  = fmaf(av, u1.x, acc[4]);  acc[5]  = fmaf(av, u1.y, acc[5]);
        acc[6]  = fmaf(av, u1.z, acc[6]);  acc[7]  = fmaf(av, u1.w, acc[7]);
        acc[8]  = fmaf(av, u2.x, acc[8]);  acc[9]  = fmaf(av, u2.y, acc[9]);
        acc[10] = fmaf(av, u2.z, acc[10]); acc[11] = fmaf(av, u2.w, acc[11]);
        acc[12] = fmaf(av, u3.x, acc[12]); acc[13] = fmaf(av, u3.y, acc[13]);
        acc[14] = fmaf(av, u3.z, acc[14]); acc[15] = fmaf(av, u3.w, acc[15]);
        acc[16] = fmaf(av, u4.x, acc[16]); acc[17] = fmaf(av, u4.y, acc[17]);
        acc[18] = fmaf(av, u4.z, acc[18]); acc[19] = fmaf(av, u4.w, acc[19]);
        acc[20] = fmaf(av, u5.x, acc[20]); acc[21] = fmaf(av, u5.y, acc[21]);
        acc[22] = fmaf(av, u5.z, acc[22]); acc[23] = fmaf(av, u5.w, acc[23]);
    };

    // ---- prologue: stage W chunk 0 (-> LDS buf0), load A group 0 (k 0..15) ----
    {
        float4 t0 = W4[gb[0]], t1 = W4[gb[1]], t2 = W4[gb[2]];
        Ws4[ib[0]] = t0; Ws4[ib[1]] = t1; Ws4[ib[2]] = t2;
    }
    float4 aA0 = *(const float4*)(srcA);
    float4 aA1 = *(const float4*)(srcA + 4);
    float4 aA2 = *(const float4*)(srcA + 8);
    float4 aA3 = *(const float4*)(srcA + 12);
    __syncthreads();

    int buf = 0;
    float4 wn0, wn1, wn2;                           // W prefetch, lives across halves
    for (int g = 0; g < 12; ++g) {                  // 12 groups of 16 k (2 per W chunk)
        const int ch = g >> 1, half = g & 1;
        if (half == 0 && ch < 5) {                  // issue next W chunk's loads
            const int gg = (ch + 1) * 192;
            wn0 = W4[gb[0] + gg]; wn1 = W4[gb[1] + gg]; wn2 = W4[gb[2] + gg];
        }
        float4 aB0, aB1, aB2, aB3;
        if (g < 11) {                               // issue next A group's loads
            const float* sa = srcA + ((g + 1) << 4);
            aB0 = *(const float4*)(sa);
            aB1 = *(const float4*)(sa + 4);
            aB2 = *(const float4*)(sa + 8);
            aB3 = *(const float4*)(sa + 12);
        }
        // compute 16 k-rows: W rows wave-uniform broadcast from LDS
        const float4* wrow = Ws4 + buf*768 + wu*192 + half*96;
        fma24row(aA0.x, wrow);      fma24row(aA0.y, wrow + 6);
        fma24row(aA0.z, wrow + 12); fma24row(aA0.w, wrow + 18);
        fma24row(aA1.x, wrow + 24); fma24row(aA1.y, wrow + 30);
        fma24row(aA1.z, wrow + 36); fma24row(aA1.w, wrow + 42);
        fma24row(aA2.x, wrow + 48); fma24row(aA2.y, wrow + 54);
        fma24row(aA2.z, wrow + 60); fma24row(aA2.w, wrow + 66);
        fma24row(aA3.x, wrow + 72); fma24row(aA3.y, wrow + 78);
        fma24row(aA3.z, wrow + 84); fma24row(aA3.w, wrow + 90);

        if (half == 1) {                            // chunk done: swap W buffers
            __syncthreads();                        // all reads of buf done
            if (ch < 5) {
                Ws4[(buf ^ 1)*768 + ib[0]] = wn0;
                Ws4[(buf ^ 1)*768 + ib[1]] = wn1;
                Ws4[(buf ^ 1)*768 + ib[2]] = wn2;
                __syncthreads();                    // buf^1 ready
                buf ^= 1;
            }
        }
        if (g < 11) { aA0 = aB0; aA1 = aB1; aA2 = aB2; aA3 = aB3; }
    }

    // ---- fold 4 wave-partials in fixed order, sigmoid, masked store (verified) ----
    {
        float* p = Pr + ((wu << 6) + lane)*25;
        #pragma unroll
        for (int l = 0; l < NL; ++l) p[l] = acc[l];
    }
    __syncthreads();

    const int* tm = tlm + b*NS + tile;
    float* Eb = E + (size_t)(b*NS + tile)*NL;
    #pragma unroll
    for (int i = 0; i < 6; ++i) {
        int o = tid + (i << 8);                     // 0..1535 (64 tok x 24 lab)
        int t = o / NL, l = o - t*NL;
        if (tm[t]) {
            float s = ((Pr[t*25 + l] + Pr[(64 + t)*25 + l])
                       + Pr[(128 + t)*25 + l]) + Pr[(192 + t)*25 + l];
            float x = s + bias[l];
            Eb[o] = 1.0f/(1.0f + expf(-x));
        }
    }
}

// ---------------- Kernel B: masked Viterbi decode, one block (256 thr) per batch ----
// Round-4 version verbatim (probe-measured 33.5 us, passed): 2-lanes-per-tag split,
// 12 ds_bpermute per step, permlane32_swap combine.
__global__ __launch_bounds__(256) void ner_viterbi(
    const float* __restrict__ E, const int* __restrict__ tlm,
    const float* __restrict__ trans, const float* __restrict__ st,
    const float* __restrict__ en, int* __restrict__ out)
{
    const int tid = threadIdx.x;
    const int b   = blockIdx.x;
    const int bS  = b*NS;

    __shared__ __align__(16) float Esh[NS*NL];   // preloaded emissions (24 KB)
    __shared__ __align__(16) float scl[NS*SCLS]; // per-step score vectors (28 KB)
    __shared__ __align__(16) float Tt[NL*NL];    // Tt[c*24+p] = T[p][c]
    __shared__ float fin[32];
    __shared__ unsigned char tr_s[NL][NS];  // trace[hypothesis][t]
    __shared__ int chosen[12];
    __shared__ int nsh, ltag;

    {
        const float4* src = (const float4*)(E + (size_t)bS*NL);
        float4* dst = (float4*)Esh;
        #pragma unroll
        for (int j = 0; j < 6; ++j) dst[tid + (j << 8)] = src[tid + (j << 8)];
    }
    for (int i = tid; i < NL*NL; i += 256) {
        int c = i / NL, p = i % NL;
        Tt[i] = trans[p*NL + c];
    }
    if (tid < 64) {   // n = lengths[b]-2 (contiguous prefix mask)
        int a = tlm[bS+tid] + tlm[bS+tid+64] + tlm[bS+tid+128] + tlm[bS+tid+192];
        #pragma unroll
        for (int off = 32; off > 0; off >>= 1) a += __shfl_down(a, off, 64);
        if (tid == 0) nsh = a;
    }
    __syncthreads();
    const int n = nsh;   // n >= 1 always

    // ---- forward: all 64 lanes of wave 0; lanes c and c+32 both own tag c ----
    if (tid < 64) {
        const int lane = tid;
        const int h    = lane >> 5;          // half: prev-tags [12h, 12h+12)
        const int c    = lane & 31;          // tag; c>=24 lanes garbage (never sourced)
        const int cidx = (c < 24) ? c : 23;  // clamped index for global reads
        const int coff = (c < 24) ? c : 24;  // scl column (24 = pad)
        const int p0   = h * 12;

        float Tc[12];
        #pragma unroll
        for (int j = 0; j < 12; ++j) Tc[j] = trans[(p0 + j)*NL + cidx];

        int idxv[12];
        #pragma unroll
        for (int j = 0; j < 12; ++j) idxv[j] = (p0 + j) << 2;

        auto bp = [](int idx4, float v) {   // pull lane (idx4/4)'s v — bit-exact
            return __int_as_float(__builtin_amdgcn_ds_bpermute(idx4, __float_as_int(v)));
        };

        float sv = st[cidx] + Esh[cidx];     // identical in lanes c and c+32
        scl[coff] = sv;                      // t=0 score vector (for backtrack)

        auto step = [&](int t, float em) {
            float cand[12];
            #pragma unroll
            for (int j = 0; j < 12; ++j)     // 12 indep bpermutes (halved DS-pipe)
                cand[j] = bp(idxv[j], sv) + Tc[j];
            float a0 = fmaxf(fmaxf(cand[0], cand[1]),  cand[2]);
            float a1 = fmaxf(fmaxf(cand[3], cand[4]),  cand[5]);
            float a2 = fmaxf(fmaxf(cand[6], cand[7]),  cand[8]);
            float a3 = fmaxf(fmaxf(cand[9], cand[10]), cand[11]);
            float pm = fmaxf(fmaxf(a0, a1), fmaxf(a2, a3));   // partial over 12 prevs
#if __has_builtin(__builtin_amdgcn_permlane32_swap)
            auto r = __builtin_amdgcn_permlane32_swap(
                         __float_as_int(pm), __float_as_int(pm), false, false);
            float best = fmaxf(__int_as_float(r[0]), __int_as_float(r[1]));
#else
            float best = fmaxf(pm, bp((lane ^ 32) << 2, pm));
#endif
            sv = best + em;
            scl[t*SCLS + coff] = sv;         // off critical path (backtrack input)
        };

        int t = 1;
        for (; t + 8 <= n; t += 8) {
            float em[8];
            const float* eb = Esh + t*NL + cidx;
            #pragma unroll
            for (int j = 0; j < 8; ++j) em[j] = eb[j*NL];   // 8 indep ds_read, imm offs
            #pragma unroll
            for (int j = 0; j < 8; ++j) step(t + j, em[j]);
        }
        for (; t < n; ++t) step(t, Esh[t*NL + cidx]);
        fin[c] = sv + en[cidx];              // c>=24 -> pad slots of fin[32]
    }
    __syncthreads();

    if (tid == 0) {   // argmax(final), first-max tie rule like jnp.argmax
        float bv = fin[0]; int bt = 0;
        #pragma unroll
        for (int cc = 1; cc < 24; ++cc) { if (fin[cc] > bv) { bv = fin[cc]; bt = cc; } }
        ltag = bt;
    }
    __syncthreads();

    // ---- backtrack: 10 windows x 24 hypotheses, recompute backpointers ----
    const int K = (n > 1) ? (n - 1 + 9) / 10 : 1;
    if (n > 1 && tid < 240) {
        const int w = tid / 24 + 1, h = tid % 24;
        int tlo = (w-1)*K; if (tlo > n-1) tlo = n-1;
        int thi = w*K;     if (thi > n-1) thi = n-1;
        int cur = h;
        for (int t = thi; t > tlo; --t) {
            const float4* sp = (const float4*)(scl + (t-1)*SCLS);
            const float4* up = (const float4*)(Tt  + cur*NL);
            float cand[24];
            #pragma unroll
            for (int i = 0; i < 6; ++i) {
                float4 s = sp[i], u = up[i];
                cand[4*i+0] = s.x + u.x;     // bitwise-identical to forward cand
                cand[4*i+1] = s.y + u.y;
                cand[4*i+2] = s.z + u.z;
                cand[4*i+3] = s.w + u.w;
            }
            float best = cand[0]; int arg = 0;
            #pragma unroll
            for (int p = 1; p < 24; ++p) { if (cand[p] > best) { best = cand[p]; arg = p; } }
            tr_s[h][t-1] = (unsigned char)arg;
            cur = arg;
        }
    }
    __syncthreads();

    if (tid == 0) {   // stitch windows
        int cur = ltag;
        for (int w = 10; w >= 1; --w) {
            chosen[w] = cur;
            int tlo = (w-1)*K; if (tlo > n-1) tlo = n-1;
            int thi = w*K;     if (thi > n-1) thi = n-1;
            if (thi > tlo) cur = tr_s[cur][tlo];
        }
    }
    __syncthreads();

    {   // emit path: t >= n-1 -> last_tag (identity backpointers on padding)
        const int t = tid;
        int tag;
        if (t >= n-1) tag = ltag;
        else { int w = t / K + 1; tag = tr_s[chosen[w]][t]; }
        out[bS + t] = tag;
    }
}

extern "C" void kernel_launch(void* const* d_in, const int* in_sizes, int n_in,
                              void* d_out, int out_size, void* d_ws, size_t ws_size,
                              hipStream_t stream) {
    const float* tf    = (const float*)d_in[0];
    const int*   tlm   = (const int*)  d_in[2];   // true_label_mask
    const float* W     = (const float*)d_in[3];
    const float* bias  = (const float*)d_in[4];
    const float* trans = (const float*)d_in[5];
    const float* st    = (const float*)d_in[6];
    const float* en    = (const float*)d_in[7];
    float* E = (float*)d_ws;                      // [128,256,24] fp32 = 3.1 MB

    ner_emis<<<dim3(NB*4), dim3(256), 0, stream>>>(tf, tlm, W, bias, E);
    ner_viterbi<<<dim3(NB), dim3(256), 0, stream>>>(E, tlm, trans, st, en, (int*)d_out);
}